// Round 6
// baseline (481.967 us; speedup 1.0000x reference)
//
#include <hip/hip_runtime.h>
#include <math.h>
#include <type_traits>

typedef __bf16 bf16_t;
typedef __bf16 bf16x8 __attribute__((ext_vector_type(8)));
typedef __bf16 bf16x4 __attribute__((ext_vector_type(4)));
typedef float  f32x4  __attribute__((ext_vector_type(4)));

#define DEVI static __device__ __forceinline__

typedef __attribute__((address_space(1))) void gvoid;
typedef __attribute__((address_space(3))) void lvoid;

DEVI bf16_t f2bf(float f) {
    unsigned u = __builtin_bit_cast(unsigned, f);
    u += 0x7fffu + ((u >> 16) & 1u);            // RNE
    unsigned short s = (unsigned short)(u >> 16);
    return __builtin_bit_cast(bf16_t, s);
}
DEVI float gelu_f(float x) { return 0.5f * x * (1.0f + erff(x * 0.7071067811865476f)); }

// ---------------------------------------------------------------------------
// Weight transpose + f32->bf16:  in [K,N] f32  ->  out [N,K] bf16
// ---------------------------------------------------------------------------
__global__ __launch_bounds__(256)
void k_transpose_cvt(const float* __restrict__ in, bf16_t* __restrict__ out, int K, int N) {
    __shared__ float t[32][33];
    const int n0 = blockIdx.x * 32, k0 = blockIdx.y * 32;
    const int tx = threadIdx.x, ty = threadIdx.y;
    for (int i = ty; i < 32; i += 8)
        t[i][tx] = in[(size_t)(k0 + i) * N + n0 + tx];
    __syncthreads();
    for (int i = ty; i < 32; i += 8)
        out[(size_t)(n0 + i) * K + k0 + tx] = f2bf(t[tx][i]);
}

// ---------------------------------------------------------------------------
// V pre-transpose: qkv [B,T,1536] (V = cols 1024..1535) -> vtg [B,512,2048]
// ---------------------------------------------------------------------------
__global__ __launch_bounds__(256)
void k_vtrans(const bf16_t* __restrict__ qkv, bf16_t* __restrict__ vtg) {
    __shared__ bf16_t t[32][33];
    const int t0 = blockIdx.x * 32, d0 = blockIdx.y * 32, b = blockIdx.z;
    const int tx = threadIdx.x, ty = threadIdx.y;
    const bf16_t* src = qkv + ((size_t)b * 2048) * 1536 + 1024;
    for (int i = ty; i < 32; i += 8)
        t[i][tx] = src[(size_t)(t0 + i) * 1536 + d0 + tx];
    __syncthreads();
    bf16_t* dst = vtg + ((size_t)b * 512) * 2048;
    for (int i = ty; i < 32; i += 8)
        dst[(size_t)(d0 + i) * 2048 + t0 + tx] = t[tx][i];
}

// ---------------------------------------------------------------------------
// f32 -> bf16 copy (vectorized, 8/thread)
// ---------------------------------------------------------------------------
__global__ __launch_bounds__(256)
void k_cvt(const float* __restrict__ in, bf16_t* __restrict__ out, int n) {
    const int i = (blockIdx.x * 256 + threadIdx.x) * 8;
    if (i >= n) return;
    float4 a = *(const float4*)(in + i);
    float4 b = *(const float4*)(in + i + 4);
    bf16x8 o = { f2bf(a.x), f2bf(a.y), f2bf(a.z), f2bf(a.w),
                 f2bf(b.x), f2bf(b.y), f2bf(b.z), f2bf(b.w) };
    *(bf16x8*)(out + i) = o;
}

// ---------------------------------------------------------------------------
// bf16 GEMM: C = A[M,K(lda)] * Bt[N,K(ldb)]^T (+bias)
// BM=128, BN in {128,64}, BK=32, 4 waves, 16x16x32 MFMA, global_load_lds.
// BN=128: wave owns 64x64 (acc 4x4). BN=64: wave owns 64x32 (acc 4x2) —
// halves LDS to 24 KB and doubles grid for skinny-N shapes (occupancy fix).
// blockIdx.z = split-K slice: A/Bt advance by z*K; f32 out goes to Cf0/Cf1.
// OUTMODE: 0 -> f32 out, 1 -> bf16 out, 2 -> bf16 out with exact GELU
// ---------------------------------------------------------------------------
template<int OUTMODE, int BN>
__global__ __launch_bounds__(256)
void k_gemm(const bf16_t* __restrict__ A, int lda, const bf16_t* __restrict__ Bt, int ldb,
            const float* __restrict__ bias, float* __restrict__ Cf0, float* __restrict__ Cf1,
            bf16_t* __restrict__ Cb, int M, int N, int K) {
    constexpr int NF = BN / 32;                    // n-frags per wave
    __shared__ __align__(16) bf16_t As[2][4096];   // [128][32]
    __shared__ __align__(16) bf16_t Bs[2][BN * 32];
    A  += (size_t)blockIdx.z * K;
    Bt += (size_t)blockIdx.z * K;
    float* __restrict__ Cf = blockIdx.z ? Cf1 : Cf0;

    const int tid = threadIdx.x;
    const int wave = tid >> 6, lane = tid & 63;
    const int lg = lane >> 4, l15 = lane & 15;
    const int m0 = blockIdx.y << 7, n0 = blockIdx.x * BN;
    const int wr = (wave >> 1) * 64, wc = (wave & 1) * (BN / 2);

    f32x4 acc[4][NF] = {};

    auto stage = [&](int buf, int k0) {
#pragma unroll
        for (int j = 0; j < 2; j++) {              // A tile: 128x32
            const int seg = j * 4 + wave;
            const int e = seg * 512 + lane * 8;
            const int r = e >> 5, c = e & 31;
            __builtin_amdgcn_global_load_lds(
                (gvoid*)(A + (size_t)(m0 + r) * lda + k0 + c),
                (lvoid*)(As[buf] + seg * 512), 16, 0, 0);
        }
#pragma unroll
        for (int j = 0; j < BN / 64; j++) {        // B tile: BNx32
            const int seg = j * 4 + wave;
            const int e = seg * 512 + lane * 8;
            const int r = e >> 5, c = e & 31;
            __builtin_amdgcn_global_load_lds(
                (gvoid*)(Bt + (size_t)(n0 + r) * ldb + k0 + c),
                (lvoid*)(Bs[buf] + seg * 512), 16, 0, 0);
        }
    };

    const int nk = K >> 5;
    stage(0, 0);
    for (int kt = 0; kt < nk; ++kt) {
        const int cur = kt & 1;
        if (kt + 1 < nk) stage(cur ^ 1, (kt + 1) << 5);
        __syncthreads();               // drains vmcnt -> staged data visible
        bf16x8 af[4], bfr[NF];
#pragma unroll
        for (int i = 0; i < 4; i++)
            af[i]  = *(const bf16x8*)(As[cur] + (wr + i * 16 + l15) * 32 + lg * 8);
#pragma unroll
        for (int j = 0; j < NF; j++)
            bfr[j] = *(const bf16x8*)(Bs[cur] + (wc + j * 16 + l15) * 32 + lg * 8);
#pragma unroll
        for (int i = 0; i < 4; i++)
#pragma unroll
            for (int j = 0; j < NF; j++)
                acc[i][j] = __builtin_amdgcn_mfma_f32_16x16x32_bf16(af[i], bfr[j], acc[i][j], 0, 0, 0);
        __syncthreads();               // all reads done before next overwrite
    }

    // epilogue: C/D layout col = lane&15, row = (lane>>4)*4 + reg
#pragma unroll
    for (int i = 0; i < 4; i++) {
        const int row0 = m0 + wr + i * 16 + lg * 4;
#pragma unroll
        for (int j = 0; j < NF; j++) {
            const int col = n0 + wc + j * 16 + l15;
            const float bs = bias ? bias[col] : 0.f;
#pragma unroll
            for (int r = 0; r < 4; r++) {
                float v = acc[i][j][r] + bs;
                if (OUTMODE == 2) v = gelu_f(v);
                const size_t idx = (size_t)(row0 + r) * N + col;
                if (OUTMODE == 0) Cf[idx] = v;
                else              Cb[idx] = f2bf(v);
            }
        }
    }
}

// ---------------------------------------------------------------------------
// Causal flash attention, bf16 MFMA.  qkv [B,T,3D] bf16 (Q,K), vtg [B,512,2048]
// bf16 (pre-transposed V), ao [B,T,D] bf16.
// 256 thr (4 waves), QBLK=64 (16 q-rows/wave), KV tiles of 64.
// K LDS rows permuted pi(t)=(t&3)*16+(t>>2): lane (j,l15) holds score vs
// t=l15*4+j -> each lane's 4 P-values are k-contiguous -> packed b64 P-store.
// All LDS tiles XOR-swizzled; all stores vectorized (no scatter).
// ---------------------------------------------------------------------------
__global__ __launch_bounds__(256)
void k_attn(const bf16_t* __restrict__ qkv, const bf16_t* __restrict__ vtg,
            bf16_t* __restrict__ ao) {
    const int bh = blockIdx.x;                 // 0..31
    const int b = bh >> 3, h = bh & 7;
    const int qi = 31 - (int)blockIdx.y;       // heavy blocks dispatch first
    const int q0 = qi << 6;
    const int tid = threadIdx.x;
    const int wave = tid >> 6, lane = tid & 63;
    const int lg = lane >> 4, l15 = lane & 15;

    __shared__ __align__(16) bf16_t Ks[64 * 64];    // row pi(t), d-swizzled
    __shared__ __align__(16) bf16_t Vt[64 * 64];    // [d][t], t-swizzled
    __shared__ __align__(16) bf16_t Ps[64 * 64];    // [q][t], wave-private rows

    const bf16_t* __restrict__ qb = qkv + ((size_t)b * 2048) * 1536 + h * 64;
    const bf16_t* __restrict__ kb = qb + 512;
    const bf16_t* __restrict__ vtb = vtg + ((size_t)(b * 512 + h * 64)) * 2048;

    const int qrb = q0 + wave * 16;

    bf16x8 qf[2];
#pragma unroll
    for (int c = 0; c < 2; c++)
        qf[c] = *(const bf16x8*)(qb + (size_t)(qrb + l15) * 1536 + c * 32 + lg * 8);

    f32x4 oacc[4] = {};
    float mrun[4], lrun[4];
#pragma unroll
    for (int r = 0; r < 4; r++) { mrun[r] = -3.0e38f; lrun[r] = 0.f; }

    const float SC = 0.125f * 1.44269504088896f;    // 1/sqrt(hd) * log2(e)
    const int ntile = qi + 1;

    for (int kt = 0; kt < ntile; ++kt) {
        const int k0 = kt << 6;
        // ---- stage K (rows permuted) and Vt tiles, all vector writes
#pragma unroll
        for (int it = 0; it < 2; ++it) {
            const int e = (it * 256 + tid) * 8;
            const int rr = e >> 6, cc = e & 63;
            bf16x8 kv = *(const bf16x8*)(kb + (size_t)(k0 + rr) * 1536 + cc);
            const int p = (rr & 3) * 16 + (rr >> 2);          // pi(t)
            *(bf16x8*)(Ks + p * 64 + (cc ^ ((p & 7) << 3))) = kv;
            bf16x8 vv = *(const bf16x8*)(vtb + (size_t)rr * 2048 + k0 + cc);
            *(bf16x8*)(Vt + rr * 64 + (cc ^ ((rr & 7) << 3))) = vv;
        }
        __syncthreads();

        // ---- S = Q K^T  (MFMA j covers t = l15*4 + j)
        f32x4 sacc[4] = {};
#pragma unroll
        for (int j = 0; j < 4; j++) {
            const int trow = j * 16 + l15;                    // physical Ks row
#pragma unroll
            for (int c = 0; c < 2; c++) {
                bf16x8 kf = *(const bf16x8*)(Ks + trow * 64 + ((c * 32 + lg * 8) ^ ((trow & 7) << 3)));
                sacc[j] = __builtin_amdgcn_mfma_f32_16x16x32_bf16(qf[c], kf, sacc[j], 0, 0, 0);
            }
        }

        // ---- online softmax (log2 domain), mask only on the diagonal tile
        auto smax = [&](auto DIAGC) {
            constexpr bool DIAG = DIAGC.value;
#pragma unroll
            for (int r = 0; r < 4; r++) {
                const int qg = qrb + lg * 4 + r;
                float s[4];
#pragma unroll
                for (int j = 0; j < 4; j++) {
                    float v = sacc[j][r] * SC;
                    if (DIAG) {
                        const int kg = k0 + l15 * 4 + j;      // t = l15*4 + j
                        v = (kg <= qg) ? v : -3.0e38f;
                    }
                    s[j] = v;
                }
                float v = fmaxf(fmaxf(s[0], s[1]), fmaxf(s[2], s[3]));
                v = fmaxf(v, __shfl_xor(v, 1));
                v = fmaxf(v, __shfl_xor(v, 2));
                v = fmaxf(v, __shfl_xor(v, 4));
                v = fmaxf(v, __shfl_xor(v, 8));
                const float mnew = fmaxf(mrun[r], v);
                const float sc = exp2f(mrun[r] - mnew);
                mrun[r] = mnew;
                lrun[r] *= sc;
#pragma unroll
                for (int df = 0; df < 4; df++) oacc[df][r] *= sc;
                const int ql = wave * 16 + lg * 4 + r;
                bf16x4 pk;
#pragma unroll
                for (int j = 0; j < 4; j++) {
                    const float p = exp2f(s[j] - mnew);
                    lrun[r] += p;
                    pk[j] = f2bf(p);
                }
                // packed store: cols l15*4..+3 hold t = l15*4..+3 (identity)
                *(bf16x4*)(Ps + ql * 64 + ((l15 * 4) ^ ((ql & 7) << 3))) = pk;
            }
        };
        if (kt == ntile - 1) smax(std::integral_constant<bool, true>{});
        else                 smax(std::integral_constant<bool, false>{});

        // ---- O += P V  (Ps rows wave-private; barrier below orders WAR)
#pragma unroll
        for (int kc = 0; kc < 2; kc++) {
            const int ql2 = wave * 16 + l15;
            bf16x8 pa = *(const bf16x8*)(Ps + ql2 * 64 + ((kc * 32 + lg * 8) ^ ((ql2 & 7) << 3)));
#pragma unroll
            for (int df = 0; df < 4; df++) {
                const int d = df * 16 + l15;
                bf16x8 vf = *(const bf16x8*)(Vt + d * 64 + ((kc * 32 + lg * 8) ^ ((d & 7) << 3)));
                oacc[df] = __builtin_amdgcn_mfma_f32_16x16x32_bf16(pa, vf, oacc[df], 0, 0, 0);
            }
        }
        __syncthreads();
    }

    // ---- epilogue
#pragma unroll
    for (int r = 0; r < 4; r++) {
        float l = lrun[r];
        l += __shfl_xor(l, 1); l += __shfl_xor(l, 2);
        l += __shfl_xor(l, 4); l += __shfl_xor(l, 8);
        lrun[r] = 1.0f / l;
    }
    bf16_t* __restrict__ aob = ao + ((size_t)b * 2048) * 512 + h * 64;
#pragma unroll
    for (int df = 0; df < 4; df++) {
        const int d = df * 16 + l15;
#pragma unroll
        for (int r = 0; r < 4; r++) {
            const int q = qrb + lg * 4 + r;
            aob[(size_t)q * 512 + d] = f2bf(oacc[df][r] * lrun[r]);
        }
    }
}

// ---------------------------------------------------------------------------
// LayerNorm helpers (block = 128 threads = 2 waves, one row of 512)
// ---------------------------------------------------------------------------
DEVI void red2(float& a, float& b, float* sh) {
#pragma unroll
    for (int m = 1; m < 64; m <<= 1) { a += __shfl_xor(a, m); b += __shfl_xor(b, m); }
    const int wv = threadIdx.x >> 6, ln = threadIdx.x & 63;
    __syncthreads();
    if (ln == 0) { sh[wv * 2] = a; sh[wv * 2 + 1] = b; }
    __syncthreads();
    a = sh[0] + sh[2];
    b = sh[1] + sh[3];
}

// out = LN(xa + p0 [+ p1] [+ bias])
template<bool WB>
__global__ __launch_bounds__(128)
void k_ln_add(const float* __restrict__ xa, const float* __restrict__ p0,
              const float* __restrict__ p1, const float* __restrict__ bias,
              const float* __restrict__ g, const float* __restrict__ be,
              float* __restrict__ outf, bf16_t* __restrict__ outb) {
    __shared__ float sh[4];
    const int row = blockIdx.x, tid = threadIdx.x;
    const size_t base = (size_t)row * 512 + tid * 4;
    float4 a = *(const float4*)(xa + base);
    float4 b = *(const float4*)(p0 + base);
    float sx = a.x + b.x, sy = a.y + b.y, sz = a.z + b.z, sw = a.w + b.w;
    if (p1) {
        float4 c = *(const float4*)(p1 + base);
        sx += c.x; sy += c.y; sz += c.z; sw += c.w;
    }
    if (bias) {
        float4 c = *(const float4*)(bias + tid * 4);
        sx += c.x; sy += c.y; sz += c.z; sw += c.w;
    }
    float sm = sx + sy + sz + sw;
    float sq = sx * sx + sy * sy + sz * sz + sw * sw;
    red2(sm, sq, sh);
    const float mean = sm * (1.f / 512.f);
    const float var = sq * (1.f / 512.f) - mean * mean;
    const float rs = rsqrtf(var + 1e-5f);
    float4 gv = *(const float4*)(g + tid * 4);
    float4 bv = *(const float4*)(be + tid * 4);
    float4 o;
    o.x = (sx - mean) * rs * gv.x + bv.x;
    o.y = (sy - mean) * rs * gv.y + bv.y;
    o.z = (sz - mean) * rs * gv.z + bv.z;
    o.w = (sw - mean) * rs * gv.w + bv.w;
    *(float4*)(outf + base) = o;
    if (WB) {
        bf16x4 ob = { f2bf(o.x), f2bf(o.y), f2bf(o.z), f2bf(o.w) };
        *(bf16x4*)(outb + base) = ob;
    }
}

DEVI float sigm(float x) { return 1.f / (1.f + expf(-x)); }

// x2 = LN2( x1 + LN_seq(seq_local + carry*dec^(tl+1)) ); outf aliases x1 ok.
// Fuses the scan carry-apply pass (seq = local-scan value in sqo).
__global__ __launch_bounds__(128)
void k_ln_seq(const float* __restrict__ sqo, const float* __restrict__ carry,
              const float* __restrict__ dl, const float* __restrict__ x1,
              const float* __restrict__ sg, const float* __restrict__ sb,
              const float* __restrict__ g2, const float* __restrict__ b2,
              float* __restrict__ outf, bf16_t* __restrict__ outb) {
    __shared__ float sh[4];
    const int row = blockIdx.x, tid = threadIdx.x;
    const size_t base = (size_t)row * 512 + tid * 4;
    const int bb = row >> 11, t = row & 2047;
    const int chunk = t >> 7, tl = t & 127;
    const float dec = sigm(dl[0]);
    const float fpow = exp2f(log2f(dec) * (float)(tl + 1));
    float4 cv = *(const float4*)(carry + (size_t)(bb * 16 + chunk) * 512 + tid * 4);
    float4 v = *(const float4*)(sqo + base);
    v.x += cv.x * fpow; v.y += cv.y * fpow; v.z += cv.z * fpow; v.w += cv.w * fpow;
    float sm = v.x + v.y + v.z + v.w;
    float sq = v.x * v.x + v.y * v.y + v.z * v.z + v.w * v.w;
    red2(sm, sq, sh);
    float mean = sm * (1.f / 512.f);
    float var = sq * (1.f / 512.f) - mean * mean;
    float rs = rsqrtf(var + 1e-5f);
    float4 sgv = *(const float4*)(sg + tid * 4);
    float4 sbv = *(const float4*)(sb + tid * 4);
    float4 x1v = *(const float4*)(x1 + base);
    float ux = x1v.x + (v.x - mean) * rs * sgv.x + sbv.x;
    float uy = x1v.y + (v.y - mean) * rs * sgv.y + sbv.y;
    float uz = x1v.z + (v.z - mean) * rs * sgv.z + sbv.z;
    float uw = x1v.w + (v.w - mean) * rs * sgv.w + sbv.w;
    float sm2 = ux + uy + uz + uw;
    float sq2 = ux * ux + uy * uy + uz * uz + uw * uw;
    red2(sm2, sq2, sh);
    float mean2 = sm2 * (1.f / 512.f);
    float var2 = sq2 * (1.f / 512.f) - mean2 * mean2;
    float rs2 = rsqrtf(var2 + 1e-5f);
    float4 g2v = *(const float4*)(g2 + tid * 4);
    float4 b2v = *(const float4*)(b2 + tid * 4);
    float4 o;
    o.x = (ux - mean2) * rs2 * g2v.x + b2v.x;
    o.y = (uy - mean2) * rs2 * g2v.y + b2v.y;
    o.z = (uz - mean2) * rs2 * g2v.z + b2v.z;
    o.w = (uw - mean2) * rs2 * g2v.w + b2v.w;
    *(float4*)(outf + base) = o;
    bf16x4 ob = { f2bf(o.x), f2bf(o.y), f2bf(o.z), f2bf(o.w) };
    *(bf16x4*)(outb + base) = ob;
}

// ---------------------------------------------------------------------------
// Causal depthwise conv1d (k=3, left pad 2) over si = s0 + s1 + bsp:
// out[t] = w0*si[t-2] + w1*si[t-1] + w2*si[t] + cb   (padding taps = 0)
// ---------------------------------------------------------------------------
__global__ __launch_bounds__(256)
void k_conv(const float* __restrict__ s0, const float* __restrict__ s1,
            const float* __restrict__ bsp, const float* __restrict__ cw,
            const float* __restrict__ cb, bf16_t* __restrict__ out) {
    const int idx = blockIdx.x * 256 + threadIdx.x;   // exactly B*T*D/4 threads
    const int d4 = idx & 127, t = (idx >> 7) & 2047, b = idx >> 18;
    const int d = d4 * 4;
    const size_t base = ((size_t)(b * 2048 + t)) * 512 + d;
    float4 bi = *(const float4*)(bsp + d);
    float a0[4], a1[4] = {0, 0, 0, 0}, a2[4] = {0, 0, 0, 0};
    {
        float4 u = *(const float4*)(s0 + base);
        float4 v = *(const float4*)(s1 + base);
        a0[0] = u.x + v.x + bi.x; a0[1] = u.y + v.y + bi.y;
        a0[2] = u.z + v.z + bi.z; a0[3] = u.w + v.w + bi.w;
    }
    if (t >= 1) {
        float4 u = *(const float4*)(s0 + base - 512);
        float4 v = *(const float4*)(s1 + base - 512);
        a1[0] = u.x + v.x + bi.x; a1[1] = u.y + v.y + bi.y;
        a1[2] = u.z + v.z + bi.z; a1[3] = u.w + v.w + bi.w;
    }
    if (t >= 2) {
        float4 u = *(const float4*)(s0 + base - 1024);
        float4 v = *(const float4*)(s1 + base - 1024);
        a2[0] = u.x + v.x + bi.x; a2[1] = u.y + v.y + bi.y;
        a2[2] = u.z + v.z + bi.z; a2[3] = u.w + v.w + bi.w;
    }
    bf16x4 ob;
#pragma unroll
    for (int e = 0; e < 4; e++) {
        const float w0 = cw[(d + e) * 3 + 0];
        const float w1 = cw[(d + e) * 3 + 1];
        const float w2 = cw[(d + e) * 3 + 2];
        const float v = w2 * a0[e] + w1 * a1[e] + w0 * a2[e] + cb[d + e];
        ob[e] = f2bf(v);
    }
    *(bf16x4*)(out + base) = ob;
}

// ---------------------------------------------------------------------------
// Decay scan (local + carry passes; carry-apply fused into k_ln_seq).
// ---------------------------------------------------------------------------
__global__ __launch_bounds__(256)
void k_scan_local(float* __restrict__ d0, const float* __restrict__ d1,
                  const float* __restrict__ bias, float* __restrict__ tot,
                  const float* __restrict__ dl, const float* __restrict__ ss) {
    const int id = blockIdx.x * 256 + threadIdx.x;    // 4*16*512 = 32768
    const int d = id & 511, c = (id >> 9) & 15, b = id >> 13;
    const float dec = sigm(dl[0]), st = ss[0];
    const float bd = bias[d];
    const size_t base = ((size_t)(b * 2048 + c * 128)) * 512 + d;
    float s = 0.f;
    for (int t = 0; t < 128; t++) {
        const size_t off = base + (size_t)t * 512;
        s = dec * s + st * (d0[off] + d1[off] + bd);
        d0[off] = s;
    }
    tot[id] = s;
}

__global__ __launch_bounds__(256)
void k_scan_carry(float* __restrict__ tot, const float* __restrict__ dl) {
    const int id = blockIdx.x * 256 + threadIdx.x;    // 2048
    const int d = id & 511, b = id >> 9;
    const float dec = sigm(dl[0]);
    const float dec128 = powf(dec, 128.f);
    float carry = 0.f;
    for (int c = 0; c < 16; c++) {
        const size_t i = (size_t)(b * 16 + c) * 512 + d;
        const float t = tot[i];
        tot[i] = carry;                 // carry-IN for chunk c
        carry = carry * dec128 + t;
    }
}

// ---------------------------------------------------------------------------
extern "C" void kernel_launch(void* const* d_in, const int* in_sizes, int n_in,
                              void* d_out, int out_size, void* d_ws, size_t ws_size,
                              hipStream_t stream) {
    const float* x     = (const float*)d_in[0];
    const float* Wqkv  = (const float*)d_in[1];
    const float* bqkv  = (const float*)d_in[2];
    const float* Wo    = (const float*)d_in[3];
    const float* bo    = (const float*)d_in[4];
    const float* ln1_g = (const float*)d_in[5];
    const float* ln1_b = (const float*)d_in[6];
    const float* Wsp   = (const float*)d_in[7];
    const float* bsp   = (const float*)d_in[8];
    const float* convw = (const float*)d_in[9];
    const float* convb = (const float*)d_in[10];
    const float* Wt1   = (const float*)d_in[11];
    const float* bt1   = (const float*)d_in[12];
    const float* Wt2   = (const float*)d_in[13];
    const float* bt2   = (const float*)d_in[14];
    const float* sln_g = (const float*)d_in[15];
    const float* sln_b = (const float*)d_in[16];
    const float* dlog  = (const float*)d_in[17];
    const float* sstep = (const float*)d_in[18];
    const float* ln2_g = (const float*)d_in[19];
    const float* ln2_b = (const float*)d_in[20];
    const float* Wf1   = (const float*)d_in[21];
    const float* bf1   = (const float*)d_in[22];
    const float* Wf2   = (const float*)d_in[23];
    const float* bf2   = (const float*)d_in[24];
    const float* ln3_g = (const float*)d_in[25];
    const float* ln3_b = (const float*)d_in[26];

    char* ws = (char*)d_ws;
    size_t off = 0;
    auto alloc = [&](size_t bytes) -> void* {
        void* p = ws + off;
        off += (bytes + 255) & ~(size_t)255;
        return p;
    };
    bf16_t* Wqkv_t = (bf16_t*)alloc((size_t)1536 * 512 * 2);
    bf16_t* Wo_t   = (bf16_t*)alloc((size_t)512 * 512 * 2);
    bf16_t* Wsp_t  = (bf16_t*)alloc((size_t)512 * 512 * 2);
    bf16_t* Wt1_t  = (bf16_t*)alloc((size_t)1024 * 512 * 2);
    bf16_t* Wt2_t  = (bf16_t*)alloc((size_t)512 * 1024 * 2);
    bf16_t* Wf1_t  = (bf16_t*)alloc((size_t)2048 * 512 * 2);
    bf16_t* Wf2_t  = (bf16_t*)alloc((size_t)512 * 2048 * 2);
    bf16_t* actb   = (bf16_t*)alloc((size_t)8192 * 512 * 2);    // bf16 activation
    bf16_t* big    = (bf16_t*)alloc((size_t)8192 * 2048 * 2);   // qkv / h1 / f (+split-K P1)
    bf16_t* aob    = (bf16_t*)alloc((size_t)8192 * 512 * 2);    // attn out / conv out
    bf16_t* vtg    = (bf16_t*)alloc((size_t)4 * 512 * 2048 * 2);// pre-transposed V
    float*  bufA   = (float*)alloc((size_t)8192 * 512 * 4);     // split-K P0 / scan buf
    float*  X1     = (float*)alloc((size_t)8192 * 512 * 4);     // x1 then x2 (in-place)
    float*  carry  = (float*)alloc((size_t)4 * 16 * 512 * 4);

    // split-K partial-1 targets (reuse dead regions):
    float* P1a = (float*)big;                                   // Wo/Wsp time: big free
    float* P1b = (float*)(big + (size_t)8192 * 1024);           // Wt2 time: h in first half
    float* P1c = (float*)aob;                                   // Wf2 time: aob+vtg free (16.8 MB)

    const dim3 tb(32, 8);
    k_transpose_cvt<<<dim3(48, 16), tb, 0, stream>>>(Wqkv, Wqkv_t, 512, 1536);
    k_transpose_cvt<<<dim3(16, 16), tb, 0, stream>>>(Wo,   Wo_t,   512, 512);
    k_transpose_cvt<<<dim3(16, 16), tb, 0, stream>>>(Wsp,  Wsp_t,  512, 512);
    k_transpose_cvt<<<dim3(32, 16), tb, 0, stream>>>(Wt1,  Wt1_t,  512, 1024);
    k_transpose_cvt<<<dim3(16, 32), tb, 0, stream>>>(Wt2,  Wt2_t,  1024, 512);
    k_transpose_cvt<<<dim3(64, 16), tb, 0, stream>>>(Wf1,  Wf1_t,  512, 2048);
    k_transpose_cvt<<<dim3(16, 64), tb, 0, stream>>>(Wf2,  Wf2_t,  2048, 512);

    k_cvt<<<2048, 256, 0, stream>>>(x, actb, 8192 * 512);

    // qkv = x @ Wqkv + bqkv  (bf16 out)
    k_gemm<1, 128><<<dim3(12, 64, 1), 256, 0, stream>>>(actb, 512, Wqkv_t, 512, bqkv,
                                                        nullptr, nullptr, big, 8192, 1536, 512);
    // pre-transpose V for attention
    k_vtrans<<<dim3(64, 16, 4), tb, 0, stream>>>(big, vtg);
    // causal MHA
    k_attn<<<dim3(32, 32), 256, 0, stream>>>(big, vtg, aob);
    // proj = ao @ Wo (BN=64, split-K=2; bias in consumer)
    k_gemm<0, 64><<<dim3(8, 64, 2), 256, 0, stream>>>(aob, 512, Wo_t, 512, nullptr,
                                                      bufA, P1a, nullptr, 8192, 512, 256);
    // x1 = LN(x + P0 + P1 + bo)
    k_ln_add<true><<<8192, 128, 0, stream>>>(x, bufA, P1a, bo, ln1_g, ln1_b, X1, actb);
    // seq_in = x1 @ Wsp (BN=64, split-K=2)
    k_gemm<0, 64><<<dim3(8, 64, 2), 256, 0, stream>>>(actb, 512, Wsp_t, 512, nullptr,
                                                      bufA, P1a, nullptr, 8192, 512, 256);
    // causal depthwise conv over (P0+P1+bsp)  (bf16 out)
    k_conv<<<4096, 256, 0, stream>>>(bufA, P1a, bsp, convw, convb, aob);
    // h = gelu(conv @ Wt1 + bt1) (bf16, BN=64)
    k_gemm<2, 64><<<dim3(16, 64, 1), 256, 0, stream>>>(aob, 512, Wt1_t, 512, bt1,
                                                       nullptr, nullptr, big, 8192, 1024, 512);
    // delta = h @ Wt2 (BN=64, split-K=2; bias in scan)
    k_gemm<0, 64><<<dim3(8, 64, 2), 256, 0, stream>>>(big, 1024, Wt2_t, 1024, nullptr,
                                                      bufA, P1b, nullptr, 8192, 512, 512);
    // decay scan over (P0+P1+bt2): local scans + carry pass (apply fused in ln_seq)
    k_scan_local<<<128, 256, 0, stream>>>(bufA, P1b, bt2, carry, dlog, sstep);
    k_scan_carry<<<8, 256, 0, stream>>>(carry, dlog);
    // x2 = LN2(x1 + LN_seq(seq_local + carry-correction))   (X1 updated in place)
    k_ln_seq<<<8192, 128, 0, stream>>>(bufA, carry, dlog, X1, sln_g, sln_b,
                                       ln2_g, ln2_b, X1, actb);
    // f = gelu(x2 @ Wf1 + bf1) (bf16)
    k_gemm<2, 128><<<dim3(16, 64, 1), 256, 0, stream>>>(actb, 512, Wf1_t, 512, bf1,
                                                        nullptr, nullptr, big, 8192, 2048, 512);
    // ff partials = f @ Wf2 (BN=64, split-K=2); bias in final LN
    k_gemm<0, 64><<<dim3(8, 64, 2), 256, 0, stream>>>(big, 2048, Wf2_t, 2048, nullptr,
                                                      bufA, P1c, nullptr, 8192, 512, 1024);
    // out = LN3(x2 + P0 + P1 + bf2)
    k_ln_add<false><<<8192, 128, 0, stream>>>(X1, bufA, P1c, bf2, ln3_g, ln3_b,
                                              (float*)d_out, nullptr);
}

// Round 7
// 453.225 us; speedup vs baseline: 1.0634x; 1.0634x over previous
//
#include <hip/hip_runtime.h>
#include <math.h>
#include <type_traits>

typedef __bf16 bf16_t;
typedef __bf16 bf16x8 __attribute__((ext_vector_type(8)));
typedef __bf16 bf16x4 __attribute__((ext_vector_type(4)));
typedef float  f32x4  __attribute__((ext_vector_type(4)));

#define DEVI static __device__ __forceinline__

typedef __attribute__((address_space(1))) void gvoid;
typedef __attribute__((address_space(3))) void lvoid;

DEVI bf16_t f2bf(float f) {
    unsigned u = __builtin_bit_cast(unsigned, f);
    u += 0x7fffu + ((u >> 16) & 1u);            // RNE
    unsigned short s = (unsigned short)(u >> 16);
    return __builtin_bit_cast(bf16_t, s);
}
DEVI float gelu_f(float x) { return 0.5f * x * (1.0f + erff(x * 0.7071067811865476f)); }

// fenced wait+barrier: lets prefetch global_load_lds stay in flight across the
// phase boundary (unlike __syncthreads, which drains vmcnt before s_barrier).
DEVI void wait_vm0_barrier() {
    asm volatile("s_waitcnt vmcnt(0)" ::: "memory");
    __builtin_amdgcn_s_barrier();
    asm volatile("" ::: "memory");
}

// ---------------------------------------------------------------------------
// Weight transpose + f32->bf16:  in [K,N] f32  ->  out [N,K] bf16
// ---------------------------------------------------------------------------
__global__ __launch_bounds__(256)
void k_transpose_cvt(const float* __restrict__ in, bf16_t* __restrict__ out, int K, int N) {
    __shared__ float t[32][33];
    const int n0 = blockIdx.x * 32, k0 = blockIdx.y * 32;
    const int tx = threadIdx.x, ty = threadIdx.y;
    for (int i = ty; i < 32; i += 8)
        t[i][tx] = in[(size_t)(k0 + i) * N + n0 + tx];
    __syncthreads();
    for (int i = ty; i < 32; i += 8)
        out[(size_t)(n0 + i) * K + k0 + tx] = f2bf(t[tx][i]);
}

// ---------------------------------------------------------------------------
// V pre-transpose: qkv [B,T,1536] (V = cols 1024..1535) -> vtg [B,512,2048]
// ---------------------------------------------------------------------------
__global__ __launch_bounds__(256)
void k_vtrans(const bf16_t* __restrict__ qkv, bf16_t* __restrict__ vtg) {
    __shared__ bf16_t t[32][33];
    const int t0 = blockIdx.x * 32, d0 = blockIdx.y * 32, b = blockIdx.z;
    const int tx = threadIdx.x, ty = threadIdx.y;
    const bf16_t* src = qkv + ((size_t)b * 2048) * 1536 + 1024;
    for (int i = ty; i < 32; i += 8)
        t[i][tx] = src[(size_t)(t0 + i) * 1536 + d0 + tx];
    __syncthreads();
    bf16_t* dst = vtg + ((size_t)b * 512) * 2048;
    for (int i = ty; i < 32; i += 8)
        dst[(size_t)(d0 + i) * 2048 + t0 + tx] = t[tx][i];
}

// ---------------------------------------------------------------------------
// f32 -> bf16 copy (vectorized, 8/thread)
// ---------------------------------------------------------------------------
__global__ __launch_bounds__(256)
void k_cvt(const float* __restrict__ in, bf16_t* __restrict__ out, int n) {
    const int i = (blockIdx.x * 256 + threadIdx.x) * 8;
    if (i >= n) return;
    float4 a = *(const float4*)(in + i);
    float4 b = *(const float4*)(in + i + 4);
    bf16x8 o = { f2bf(a.x), f2bf(a.y), f2bf(a.z), f2bf(a.w),
                 f2bf(b.x), f2bf(b.y), f2bf(b.z), f2bf(b.w) };
    *(bf16x8*)(out + i) = o;
}

// ---------------------------------------------------------------------------
// bf16 GEMM: C = A[M,K(lda)] * Bt[N,K(ldb)]^T (+bias)
// 128x128 tile, BK=32, 4 waves, 16x16x32 MFMA, global_load_lds width 16.
// Pipelined 2-phase K-loop (T3): issue next-tile stage, compute current tile
// with the prefetch IN FLIGHT, then one vmcnt(0)+s_barrier per K-step.
// blockIdx.z = split-K slice: A/Bt advance by z*K; f32 out goes to Cf0/Cf1.
// OUTMODE: 0 -> f32 out, 1 -> bf16 out, 2 -> bf16 out with exact GELU
// ---------------------------------------------------------------------------
template<int OUTMODE>
__global__ __launch_bounds__(256)
void k_gemm(const bf16_t* __restrict__ A, int lda, const bf16_t* __restrict__ Bt, int ldb,
            const float* __restrict__ bias, float* __restrict__ Cf0, float* __restrict__ Cf1,
            bf16_t* __restrict__ Cb, int M, int N, int K) {
    __shared__ __align__(16) bf16_t As[2][4096];   // [128][32]
    __shared__ __align__(16) bf16_t Bs[2][4096];
    A  += (size_t)blockIdx.z * K;
    Bt += (size_t)blockIdx.z * K;
    float* __restrict__ Cf = blockIdx.z ? Cf1 : Cf0;

    const int tid = threadIdx.x;
    const int wave = tid >> 6, lane = tid & 63;
    const int lg = lane >> 4, l15 = lane & 15;
    const int m0 = blockIdx.y << 7, n0 = blockIdx.x << 7;
    const int wr = (wave >> 1) * 64, wc = (wave & 1) * 64;

    f32x4 acc[4][4] = {};

    auto stage = [&](int buf, int k0) {
#pragma unroll
        for (int j = 0; j < 2; j++) {
            const int seg = j * 4 + wave;                  // 0..7, wave-uniform
            const int e = seg * 512 + lane * 8;            // element in [128][32] tile
            const int r = e >> 5, c = e & 31;
            __builtin_amdgcn_global_load_lds(
                (gvoid*)(A + (size_t)(m0 + r) * lda + k0 + c),
                (lvoid*)(As[buf] + seg * 512), 16, 0, 0);
            __builtin_amdgcn_global_load_lds(
                (gvoid*)(Bt + (size_t)(n0 + r) * ldb + k0 + c),
                (lvoid*)(Bs[buf] + seg * 512), 16, 0, 0);
        }
    };

    const int nk = K >> 5;
    stage(0, 0);
    wait_vm0_barrier();                 // prologue: tile 0 resident
    for (int kt = 0; kt < nk; ++kt) {
        const int cur = kt & 1;
        if (kt + 1 < nk) stage(cur ^ 1, (kt + 1) << 5);   // prefetch stays in flight
        bf16x8 af[4], bfr[4];
#pragma unroll
        for (int i = 0; i < 4; i++) {
            af[i]  = *(const bf16x8*)(As[cur] + (wr + i * 16 + l15) * 32 + lg * 8);
            bfr[i] = *(const bf16x8*)(Bs[cur] + (wc + i * 16 + l15) * 32 + lg * 8);
        }
#pragma unroll
        for (int i = 0; i < 4; i++)
#pragma unroll
            for (int j = 0; j < 4; j++)
                acc[i][j] = __builtin_amdgcn_mfma_f32_16x16x32_bf16(af[i], bfr[j], acc[i][j], 0, 0, 0);
        // next tile landed (had the whole MFMA phase to arrive) + WAR protection
        wait_vm0_barrier();
    }

    // epilogue: C/D layout col = lane&15, row = (lane>>4)*4 + reg
#pragma unroll
    for (int i = 0; i < 4; i++) {
        const int row0 = m0 + wr + i * 16 + lg * 4;
#pragma unroll
        for (int j = 0; j < 4; j++) {
            const int col = n0 + wc + j * 16 + l15;
            const float bs = bias ? bias[col] : 0.f;
#pragma unroll
            for (int r = 0; r < 4; r++) {
                float v = acc[i][j][r] + bs;
                if (OUTMODE == 2) v = gelu_f(v);
                const size_t idx = (size_t)(row0 + r) * N + col;
                if (OUTMODE == 0) Cf[idx] = v;
                else              Cb[idx] = f2bf(v);
            }
        }
    }
}

// ---------------------------------------------------------------------------
// Causal flash attention, bf16 MFMA.  qkv [B,T,3D] bf16 (Q,K), vtg [B,512,2048]
// bf16 (pre-transposed V), ao [B,T,D] bf16.
// 256 thr (4 waves), QBLK=64 (16 q-rows/wave), KV tiles of 64.
// K LDS rows permuted pi(t)=(t&3)*16+(t>>2): lane (j,l15) holds score vs
// t=l15*4+j -> each lane's 4 P-values are k-contiguous -> packed b64 P-store.
// All LDS tiles XOR-swizzled; all stores vectorized (no scatter).
// ---------------------------------------------------------------------------
__global__ __launch_bounds__(256)
void k_attn(const bf16_t* __restrict__ qkv, const bf16_t* __restrict__ vtg,
            bf16_t* __restrict__ ao) {
    const int bh = blockIdx.x;                 // 0..31
    const int b = bh >> 3, h = bh & 7;
    const int qi = 31 - (int)blockIdx.y;       // heavy blocks dispatch first
    const int q0 = qi << 6;
    const int tid = threadIdx.x;
    const int wave = tid >> 6, lane = tid & 63;
    const int lg = lane >> 4, l15 = lane & 15;

    __shared__ __align__(16) bf16_t Ks[64 * 64];    // row pi(t), d-swizzled
    __shared__ __align__(16) bf16_t Vt[64 * 64];    // [d][t], t-swizzled
    __shared__ __align__(16) bf16_t Ps[64 * 64];    // [q][t], wave-private rows

    const bf16_t* __restrict__ qb = qkv + ((size_t)b * 2048) * 1536 + h * 64;
    const bf16_t* __restrict__ kb = qb + 512;
    const bf16_t* __restrict__ vtb = vtg + ((size_t)(b * 512 + h * 64)) * 2048;

    const int qrb = q0 + wave * 16;

    bf16x8 qf[2];
#pragma unroll
    for (int c = 0; c < 2; c++)
        qf[c] = *(const bf16x8*)(qb + (size_t)(qrb + l15) * 1536 + c * 32 + lg * 8);

    f32x4 oacc[4] = {};
    float mrun[4], lrun[4];
#pragma unroll
    for (int r = 0; r < 4; r++) { mrun[r] = -3.0e38f; lrun[r] = 0.f; }

    const float SC = 0.125f * 1.44269504088896f;    // 1/sqrt(hd) * log2(e)
    const int ntile = qi + 1;

    for (int kt = 0; kt < ntile; ++kt) {
        const int k0 = kt << 6;
        // ---- stage K (rows permuted) and Vt tiles, all vector writes
#pragma unroll
        for (int it = 0; it < 2; ++it) {
            const int e = (it * 256 + tid) * 8;
            const int rr = e >> 6, cc = e & 63;
            bf16x8 kv = *(const bf16x8*)(kb + (size_t)(k0 + rr) * 1536 + cc);
            const int p = (rr & 3) * 16 + (rr >> 2);          // pi(t)
            *(bf16x8*)(Ks + p * 64 + (cc ^ ((p & 7) << 3))) = kv;
            bf16x8 vv = *(const bf16x8*)(vtb + (size_t)rr * 2048 + k0 + cc);
            *(bf16x8*)(Vt + rr * 64 + (cc ^ ((rr & 7) << 3))) = vv;
        }
        __syncthreads();

        // ---- S = Q K^T  (MFMA j covers t = l15*4 + j)
        f32x4 sacc[4] = {};
#pragma unroll
        for (int j = 0; j < 4; j++) {
            const int trow = j * 16 + l15;                    // physical Ks row
#pragma unroll
            for (int c = 0; c < 2; c++) {
                bf16x8 kf = *(const bf16x8*)(Ks + trow * 64 + ((c * 32 + lg * 8) ^ ((trow & 7) << 3)));
                sacc[j] = __builtin_amdgcn_mfma_f32_16x16x32_bf16(qf[c], kf, sacc[j], 0, 0, 0);
            }
        }

        // ---- online softmax (log2 domain), mask only on the diagonal tile
        auto smax = [&](auto DIAGC) {
            constexpr bool DIAG = DIAGC.value;
#pragma unroll
            for (int r = 0; r < 4; r++) {
                const int qg = qrb + lg * 4 + r;
                float s[4];
#pragma unroll
                for (int j = 0; j < 4; j++) {
                    float v = sacc[j][r] * SC;
                    if (DIAG) {
                        const int kg = k0 + l15 * 4 + j;      // t = l15*4 + j
                        v = (kg <= qg) ? v : -3.0e38f;
                    }
                    s[j] = v;
                }
                float v = fmaxf(fmaxf(s[0], s[1]), fmaxf(s[2], s[3]));
                v = fmaxf(v, __shfl_xor(v, 1));
                v = fmaxf(v, __shfl_xor(v, 2));
                v = fmaxf(v, __shfl_xor(v, 4));
                v = fmaxf(v, __shfl_xor(v, 8));
                const float mnew = fmaxf(mrun[r], v);
                const float sc = exp2f(mrun[r] - mnew);
                mrun[r] = mnew;
                lrun[r] *= sc;
#pragma unroll
                for (int df = 0; df < 4; df++) oacc[df][r] *= sc;
                const int ql = wave * 16 + lg * 4 + r;
                bf16x4 pk;
#pragma unroll
                for (int j = 0; j < 4; j++) {
                    const float p = exp2f(s[j] - mnew);
                    lrun[r] += p;
                    pk[j] = f2bf(p);
                }
                // packed store: cols l15*4..+3 hold t = l15*4..+3 (identity)
                *(bf16x4*)(Ps + ql * 64 + ((l15 * 4) ^ ((ql & 7) << 3))) = pk;
            }
        };
        if (kt == ntile - 1) smax(std::integral_constant<bool, true>{});
        else                 smax(std::integral_constant<bool, false>{});

        // ---- O += P V  (Ps rows wave-private; barrier below orders WAR)
#pragma unroll
        for (int kc = 0; kc < 2; kc++) {
            const int ql2 = wave * 16 + l15;
            bf16x8 pa = *(const bf16x8*)(Ps + ql2 * 64 + ((kc * 32 + lg * 8) ^ ((ql2 & 7) << 3)));
#pragma unroll
            for (int df = 0; df < 4; df++) {
                const int d = df * 16 + l15;
                bf16x8 vf = *(const bf16x8*)(Vt + d * 64 + ((kc * 32 + lg * 8) ^ ((d & 7) << 3)));
                oacc[df] = __builtin_amdgcn_mfma_f32_16x16x32_bf16(pa, vf, oacc[df], 0, 0, 0);
            }
        }
        __syncthreads();
    }

    // ---- epilogue
#pragma unroll
    for (int r = 0; r < 4; r++) {
        float l = lrun[r];
        l += __shfl_xor(l, 1); l += __shfl_xor(l, 2);
        l += __shfl_xor(l, 4); l += __shfl_xor(l, 8);
        lrun[r] = 1.0f / l;
    }
    bf16_t* __restrict__ aob = ao + ((size_t)b * 2048) * 512 + h * 64;
#pragma unroll
    for (int df = 0; df < 4; df++) {
        const int d = df * 16 + l15;
#pragma unroll
        for (int r = 0; r < 4; r++) {
            const int q = qrb + lg * 4 + r;
            aob[(size_t)q * 512 + d] = f2bf(oacc[df][r] * lrun[r]);
        }
    }
}

// ---------------------------------------------------------------------------
// LayerNorm helpers (block = 128 threads = 2 waves, one row of 512)
// ---------------------------------------------------------------------------
DEVI void red2(float& a, float& b, float* sh) {
#pragma unroll
    for (int m = 1; m < 64; m <<= 1) { a += __shfl_xor(a, m); b += __shfl_xor(b, m); }
    const int wv = threadIdx.x >> 6, ln = threadIdx.x & 63;
    __syncthreads();
    if (ln == 0) { sh[wv * 2] = a; sh[wv * 2 + 1] = b; }
    __syncthreads();
    a = sh[0] + sh[2];
    b = sh[1] + sh[3];
}

// out = LN(xa + p0 [+ p1] [+ bias])
template<bool WB>
__global__ __launch_bounds__(128)
void k_ln_add(const float* __restrict__ xa, const float* __restrict__ p0,
              const float* __restrict__ p1, const float* __restrict__ bias,
              const float* __restrict__ g, const float* __restrict__ be,
              float* __restrict__ outf, bf16_t* __restrict__ outb) {
    __shared__ float sh[4];
    const int row = blockIdx.x, tid = threadIdx.x;
    const size_t base = (size_t)row * 512 + tid * 4;
    float4 a = *(const float4*)(xa + base);
    float4 b = *(const float4*)(p0 + base);
    float sx = a.x + b.x, sy = a.y + b.y, sz = a.z + b.z, sw = a.w + b.w;
    if (p1) {
        float4 c = *(const float4*)(p1 + base);
        sx += c.x; sy += c.y; sz += c.z; sw += c.w;
    }
    if (bias) {
        float4 c = *(const float4*)(bias + tid * 4);
        sx += c.x; sy += c.y; sz += c.z; sw += c.w;
    }
    float sm = sx + sy + sz + sw;
    float sq = sx * sx + sy * sy + sz * sz + sw * sw;
    red2(sm, sq, sh);
    const float mean = sm * (1.f / 512.f);
    const float var = sq * (1.f / 512.f) - mean * mean;
    const float rs = rsqrtf(var + 1e-5f);
    float4 gv = *(const float4*)(g + tid * 4);
    float4 bv = *(const float4*)(be + tid * 4);
    float4 o;
    o.x = (sx - mean) * rs * gv.x + bv.x;
    o.y = (sy - mean) * rs * gv.y + bv.y;
    o.z = (sz - mean) * rs * gv.z + bv.z;
    o.w = (sw - mean) * rs * gv.w + bv.w;
    *(float4*)(outf + base) = o;
    if (WB) {
        bf16x4 ob = { f2bf(o.x), f2bf(o.y), f2bf(o.z), f2bf(o.w) };
        *(bf16x4*)(outb + base) = ob;
    }
}

DEVI float sigm(float x) { return 1.f / (1.f + expf(-x)); }

// x2 = LN2( x1 + LN_seq(seq_local + carry*dec^(tl+1)) ); outf aliases x1 ok.
// Fuses the scan carry-apply pass (seq = local-scan value in sqo).
__global__ __launch_bounds__(128)
void k_ln_seq(const float* __restrict__ sqo, const float* __restrict__ carry,
              const float* __restrict__ dl, const float* __restrict__ x1,
              const float* __restrict__ sg, const float* __restrict__ sb,
              const float* __restrict__ g2, const float* __restrict__ b2,
              float* __restrict__ outf, bf16_t* __restrict__ outb) {
    __shared__ float sh[4];
    const int row = blockIdx.x, tid = threadIdx.x;
    const size_t base = (size_t)row * 512 + tid * 4;
    const int bb = row >> 11, t = row & 2047;
    const int chunk = t >> 7, tl = t & 127;
    const float dec = sigm(dl[0]);
    const float fpow = exp2f(log2f(dec) * (float)(tl + 1));
    float4 cv = *(const float4*)(carry + (size_t)(bb * 16 + chunk) * 512 + tid * 4);
    float4 v = *(const float4*)(sqo + base);
    v.x += cv.x * fpow; v.y += cv.y * fpow; v.z += cv.z * fpow; v.w += cv.w * fpow;
    float sm = v.x + v.y + v.z + v.w;
    float sq = v.x * v.x + v.y * v.y + v.z * v.z + v.w * v.w;
    red2(sm, sq, sh);
    float mean = sm * (1.f / 512.f);
    float var = sq * (1.f / 512.f) - mean * mean;
    float rs = rsqrtf(var + 1e-5f);
    float4 sgv = *(const float4*)(sg + tid * 4);
    float4 sbv = *(const float4*)(sb + tid * 4);
    float4 x1v = *(const float4*)(x1 + base);
    float ux = x1v.x + (v.x - mean) * rs * sgv.x + sbv.x;
    float uy = x1v.y + (v.y - mean) * rs * sgv.y + sbv.y;
    float uz = x1v.z + (v.z - mean) * rs * sgv.z + sbv.z;
    float uw = x1v.w + (v.w - mean) * rs * sgv.w + sbv.w;
    float sm2 = ux + uy + uz + uw;
    float sq2 = ux * ux + uy * uy + uz * uz + uw * uw;
    red2(sm2, sq2, sh);
    float mean2 = sm2 * (1.f / 512.f);
    float var2 = sq2 * (1.f / 512.f) - mean2 * mean2;
    float rs2 = rsqrtf(var2 + 1e-5f);
    float4 g2v = *(const float4*)(g2 + tid * 4);
    float4 b2v = *(const float4*)(b2 + tid * 4);
    float4 o;
    o.x = (ux - mean2) * rs2 * g2v.x + b2v.x;
    o.y = (uy - mean2) * rs2 * g2v.y + b2v.y;
    o.z = (uz - mean2) * rs2 * g2v.z + b2v.z;
    o.w = (uw - mean2) * rs2 * g2v.w + b2v.w;
    *(float4*)(outf + base) = o;
    bf16x4 ob = { f2bf(o.x), f2bf(o.y), f2bf(o.z), f2bf(o.w) };
    *(bf16x4*)(outb + base) = ob;
}

// ---------------------------------------------------------------------------
// Causal depthwise conv1d (k=3, left pad 2) over si = s0 + s1 + bsp:
// out[t] = w0*si[t-2] + w1*si[t-1] + w2*si[t] + cb   (padding taps = 0)
// ---------------------------------------------------------------------------
__global__ __launch_bounds__(256)
void k_conv(const float* __restrict__ s0, const float* __restrict__ s1,
            const float* __restrict__ bsp, const float* __restrict__ cw,
            const float* __restrict__ cb, bf16_t* __restrict__ out) {
    const int idx = blockIdx.x * 256 + threadIdx.x;   // exactly B*T*D/4 threads
    const int d4 = idx & 127, t = (idx >> 7) & 2047, b = idx >> 18;
    const int d = d4 * 4;
    const size_t base = ((size_t)(b * 2048 + t)) * 512 + d;
    float4 bi = *(const float4*)(bsp + d);
    float a0[4], a1[4] = {0, 0, 0, 0}, a2[4] = {0, 0, 0, 0};
    {
        float4 u = *(const float4*)(s0 + base);
        float4 v = *(const float4*)(s1 + base);
        a0[0] = u.x + v.x + bi.x; a0[1] = u.y + v.y + bi.y;
        a0[2] = u.z + v.z + bi.z; a0[3] = u.w + v.w + bi.w;
    }
    if (t >= 1) {
        float4 u = *(const float4*)(s0 + base - 512);
        float4 v = *(const float4*)(s1 + base - 512);
        a1[0] = u.x + v.x + bi.x; a1[1] = u.y + v.y + bi.y;
        a1[2] = u.z + v.z + bi.z; a1[3] = u.w + v.w + bi.w;
    }
    if (t >= 2) {
        float4 u = *(const float4*)(s0 + base - 1024);
        float4 v = *(const float4*)(s1 + base - 1024);
        a2[0] = u.x + v.x + bi.x; a2[1] = u.y + v.y + bi.y;
        a2[2] = u.z + v.z + bi.z; a2[3] = u.w + v.w + bi.w;
    }
    bf16x4 ob;
#pragma unroll
    for (int e = 0; e < 4; e++) {
        const float w0 = cw[(d + e) * 3 + 0];
        const float w1 = cw[(d + e) * 3 + 1];
        const float w2 = cw[(d + e) * 3 + 2];
        const float v = w2 * a0[e] + w1 * a1[e] + w0 * a2[e] + cb[d + e];
        ob[e] = f2bf(v);
    }
    *(bf16x4*)(out + base) = ob;
}

// ---------------------------------------------------------------------------
// Decay scan (local + carry passes; carry-apply fused into k_ln_seq).
// ---------------------------------------------------------------------------
__global__ __launch_bounds__(256)
void k_scan_local(float* __restrict__ d0, const float* __restrict__ d1,
                  const float* __restrict__ bias, float* __restrict__ tot,
                  const float* __restrict__ dl, const float* __restrict__ ss) {
    const int id = blockIdx.x * 256 + threadIdx.x;    // 4*16*512 = 32768
    const int d = id & 511, c = (id >> 9) & 15, b = id >> 13;
    const float dec = sigm(dl[0]), st = ss[0];
    const float bd = bias[d];
    const size_t base = ((size_t)(b * 2048 + c * 128)) * 512 + d;
    float s = 0.f;
    for (int t = 0; t < 128; t++) {
        const size_t off = base + (size_t)t * 512;
        s = dec * s + st * (d0[off] + d1[off] + bd);
        d0[off] = s;
    }
    tot[id] = s;
}

__global__ __launch_bounds__(256)
void k_scan_carry(float* __restrict__ tot, const float* __restrict__ dl) {
    const int id = blockIdx.x * 256 + threadIdx.x;    // 2048
    const int d = id & 511, b = id >> 9;
    const float dec = sigm(dl[0]);
    const float dec128 = powf(dec, 128.f);
    float carry = 0.f;
    for (int c = 0; c < 16; c++) {
        const size_t i = (size_t)(b * 16 + c) * 512 + d;
        const float t = tot[i];
        tot[i] = carry;                 // carry-IN for chunk c
        carry = carry * dec128 + t;
    }
}

// ---------------------------------------------------------------------------
extern "C" void kernel_launch(void* const* d_in, const int* in_sizes, int n_in,
                              void* d_out, int out_size, void* d_ws, size_t ws_size,
                              hipStream_t stream) {
    const float* x     = (const float*)d_in[0];
    const float* Wqkv  = (const float*)d_in[1];
    const float* bqkv  = (const float*)d_in[2];
    const float* Wo    = (const float*)d_in[3];
    const float* bo    = (const float*)d_in[4];
    const float* ln1_g = (const float*)d_in[5];
    const float* ln1_b = (const float*)d_in[6];
    const float* Wsp   = (const float*)d_in[7];
    const float* bsp   = (const float*)d_in[8];
    const float* convw = (const float*)d_in[9];
    const float* convb = (const float*)d_in[10];
    const float* Wt1   = (const float*)d_in[11];
    const float* bt1   = (const float*)d_in[12];
    const float* Wt2   = (const float*)d_in[13];
    const float* bt2   = (const float*)d_in[14];
    const float* sln_g = (const float*)d_in[15];
    const float* sln_b = (const float*)d_in[16];
    const float* dlog  = (const float*)d_in[17];
    const float* sstep = (const float*)d_in[18];
    const float* ln2_g = (const float*)d_in[19];
    const float* ln2_b = (const float*)d_in[20];
    const float* Wf1   = (const float*)d_in[21];
    const float* bf1   = (const float*)d_in[22];
    const float* Wf2   = (const float*)d_in[23];
    const float* bf2   = (const float*)d_in[24];
    const float* ln3_g = (const float*)d_in[25];
    const float* ln3_b = (const float*)d_in[26];

    char* ws = (char*)d_ws;
    size_t off = 0;
    auto alloc = [&](size_t bytes) -> void* {
        void* p = ws + off;
        off += (bytes + 255) & ~(size_t)255;
        return p;
    };
    bf16_t* Wqkv_t = (bf16_t*)alloc((size_t)1536 * 512 * 2);
    bf16_t* Wo_t   = (bf16_t*)alloc((size_t)512 * 512 * 2);
    bf16_t* Wsp_t  = (bf16_t*)alloc((size_t)512 * 512 * 2);
    bf16_t* Wt1_t  = (bf16_t*)alloc((size_t)1024 * 512 * 2);
    bf16_t* Wt2_t  = (bf16_t*)alloc((size_t)512 * 1024 * 2);
    bf16_t* Wf1_t  = (bf16_t*)alloc((size_t)2048 * 512 * 2);
    bf16_t* Wf2_t  = (bf16_t*)alloc((size_t)512 * 2048 * 2);
    bf16_t* actb   = (bf16_t*)alloc((size_t)8192 * 512 * 2);    // bf16 activation
    bf16_t* big    = (bf16_t*)alloc((size_t)8192 * 2048 * 2);   // qkv / h1 / f (+split-K P1)
    bf16_t* aob    = (bf16_t*)alloc((size_t)8192 * 512 * 2);    // attn out / conv out
    bf16_t* vtg    = (bf16_t*)alloc((size_t)4 * 512 * 2048 * 2);// pre-transposed V
    float*  bufA   = (float*)alloc((size_t)8192 * 512 * 4);     // split-K P0 / scan buf
    float*  X1     = (float*)alloc((size_t)8192 * 512 * 4);     // x1 then x2 (in-place)
    float*  carry  = (float*)alloc((size_t)4 * 16 * 512 * 4);

    // split-K partial-1 targets (reuse dead regions):
    float* P1a = (float*)big;                                   // Wo/Wsp time: big free
    float* P1b = (float*)(big + (size_t)8192 * 1024);           // Wt2 time: h in first half
    float* P1c = (float*)aob;                                   // Wf2 time: aob+vtg free (16.8 MB)

    const dim3 tb(32, 8);
    k_transpose_cvt<<<dim3(48, 16), tb, 0, stream>>>(Wqkv, Wqkv_t, 512, 1536);
    k_transpose_cvt<<<dim3(16, 16), tb, 0, stream>>>(Wo,   Wo_t,   512, 512);
    k_transpose_cvt<<<dim3(16, 16), tb, 0, stream>>>(Wsp,  Wsp_t,  512, 512);
    k_transpose_cvt<<<dim3(32, 16), tb, 0, stream>>>(Wt1,  Wt1_t,  512, 1024);
    k_transpose_cvt<<<dim3(16, 32), tb, 0, stream>>>(Wt2,  Wt2_t,  1024, 512);
    k_transpose_cvt<<<dim3(64, 16), tb, 0, stream>>>(Wf1,  Wf1_t,  512, 2048);
    k_transpose_cvt<<<dim3(16, 64), tb, 0, stream>>>(Wf2,  Wf2_t,  2048, 512);

    k_cvt<<<2048, 256, 0, stream>>>(x, actb, 8192 * 512);

    // qkv = x @ Wqkv + bqkv  (bf16 out)
    k_gemm<1><<<dim3(12, 64, 1), 256, 0, stream>>>(actb, 512, Wqkv_t, 512, bqkv,
                                                   nullptr, nullptr, big, 8192, 1536, 512);
    // pre-transpose V for attention
    k_vtrans<<<dim3(64, 16, 4), tb, 0, stream>>>(big, vtg);
    // causal MHA
    k_attn<<<dim3(32, 32), 256, 0, stream>>>(big, vtg, aob);
    // proj = ao @ Wo (split-K=2; bias in consumer)
    k_gemm<0><<<dim3(4, 64, 2), 256, 0, stream>>>(aob, 512, Wo_t, 512, nullptr,
                                                  bufA, P1a, nullptr, 8192, 512, 256);
    // x1 = LN(x + P0 + P1 + bo)
    k_ln_add<true><<<8192, 128, 0, stream>>>(x, bufA, P1a, bo, ln1_g, ln1_b, X1, actb);
    // seq_in = x1 @ Wsp (split-K=2)
    k_gemm<0><<<dim3(4, 64, 2), 256, 0, stream>>>(actb, 512, Wsp_t, 512, nullptr,
                                                  bufA, P1a, nullptr, 8192, 512, 256);
    // causal depthwise conv over (P0+P1+bsp)  (bf16 out)
    k_conv<<<4096, 256, 0, stream>>>(bufA, P1a, bsp, convw, convb, aob);
    // h = gelu(conv @ Wt1 + bt1) (bf16)
    k_gemm<2><<<dim3(8, 64, 1), 256, 0, stream>>>(aob, 512, Wt1_t, 512, bt1,
                                                  nullptr, nullptr, big, 8192, 1024, 512);
    // delta = h @ Wt2 (split-K=2; bias in scan)
    k_gemm<0><<<dim3(4, 64, 2), 256, 0, stream>>>(big, 1024, Wt2_t, 1024, nullptr,
                                                  bufA, P1b, nullptr, 8192, 512, 512);
    // decay scan over (P0+P1+bt2): local scans + carry pass (apply fused in ln_seq)
    k_scan_local<<<128, 256, 0, stream>>>(bufA, P1b, bt2, carry, dlog, sstep);
    k_scan_carry<<<8, 256, 0, stream>>>(carry, dlog);
    // x2 = LN2(x1 + LN_seq(seq_local + carry-correction))   (X1 updated in place)
    k_ln_seq<<<8192, 128, 0, stream>>>(bufA, carry, dlog, X1, sln_g, sln_b,
                                       ln2_g, ln2_b, X1, actb);
    // f = gelu(x2 @ Wf1 + bf1) (bf16)
    k_gemm<2><<<dim3(16, 64, 1), 256, 0, stream>>>(actb, 512, Wf1_t, 512, bf1,
                                                   nullptr, nullptr, big, 8192, 2048, 512);
    // ff partials = f @ Wf2 (split-K=2); bias in final LN
    k_gemm<0><<<dim3(4, 64, 2), 256, 0, stream>>>(big, 2048, Wf2_t, 2048, nullptr,
                                                  bufA, P1c, nullptr, 8192, 512, 1024);
    // out = LN3(x2 + P0 + P1 + bf2)
    k_ln_add<false><<<8192, 128, 0, stream>>>(X1, bufA, P1c, bf2, ln3_g, ln3_b,
                                              (float*)d_out, nullptr);
}